// Round 10
// baseline (298.567 us; speedup 1.0000x reference)
//
#include <hip/hip_runtime.h>
#include <hip/hip_bf16.h>

// GraphSAGE (2x SAGEConv mean + normalize + relu, final linear) on MI355X.
// R10: fusion round. All kernels were <40us; 9 launches + intermediate
// round-trips dominated. (1) xb table (3.2MB) already fits per-XCD L2 -> no
// pass-split needed for layer-1 gather. (2) partitionB holds the sorted bucket
// in LDS -> gather14 + dense1 fused into its epilogue (agg1 never hits global;
// sorted_src re-read deleted). (3) dense2 fused into gather32 pass-1 epilogue
// via cndmask+shfl reduce-scatter over the 4-lane node quad. 9 -> 5 kernels.

#define CHA 16384   // edges per phase-A block
#define MAXB 512    // max coarse buckets (NB = ceil(N/256) = 391)
#define CAPB 18432  // slots per bucket region (mean fill ~16.4K, ~16 sigma margin)

static __device__ __forceinline__ unsigned short f2bf(float f) {
    unsigned u = __float_as_uint(f);
    unsigned r = (u + 0x7FFFu + ((u >> 16) & 1u)) >> 16;   // RTN-even
    return (unsigned short)r;
}
#define BF_LO(u) __uint_as_float((u) << 16)
#define BF_HI(u) __uint_as_float((u) & 0xFFFF0000u)

// x [N x 14] fp32 -> xb [N x 16] bf16 (rows padded to 32B). Also inits bcursor.
__global__ void cvt_x_bf16(const float* __restrict__ x, unsigned short* __restrict__ xb,
                           int* __restrict__ bcursor, int N, int NB) {
    int idx = blockIdx.x * blockDim.x + threadIdx.x;
    if (idx < NB) bcursor[idx] = idx * CAPB;
    if (idx >= N * 16) return;
    int n = idx >> 4, f = idx & 15;
    float v = (f < 14) ? x[n * 14 + f] : 0.f;
    xb[idx] = f2bf(v);
}

// Phase A: per-block counting sort into LDS, coalesced per-run copy-out into
// the slack bucket regions. dst/src loaded ONCE as int4 into registers.
__global__ __launch_bounds__(1024) void partitionA(
        const int* __restrict__ src, const int* __restrict__ dst,
        int* __restrict__ bcursor, unsigned* __restrict__ part, int E, int NB) {
    __shared__ unsigned pk[CHA];                       // 64 KB staging
    __shared__ int h[MAXB], lofs[MAXB], cur[MAXB], delta[MAXB], tmp[MAXB];
    int t = threadIdx.x;
    int base = blockIdx.x * CHA;
    int end = base + CHA; if (end > E) end = E;
    int cnt = end - base;

    int ed[16], es[16];
    for (int i = t; i < NB; i += 1024) h[i] = 0;
    __syncthreads();
    #pragma unroll
    for (int i = 0; i < 4; ++i) {
        int j = i * 4096 + t * 4;
        if (j + 4 <= cnt) {
            int4 d4 = *(const int4*)(dst + base + j);
            int4 s4 = *(const int4*)(src + base + j);
            ed[i*4+0] = d4.x; ed[i*4+1] = d4.y; ed[i*4+2] = d4.z; ed[i*4+3] = d4.w;
            es[i*4+0] = s4.x; es[i*4+1] = s4.y; es[i*4+2] = s4.z; es[i*4+3] = s4.w;
            atomicAdd(&h[d4.x >> 8], 1);
            atomicAdd(&h[d4.y >> 8], 1);
            atomicAdd(&h[d4.z >> 8], 1);
            atomicAdd(&h[d4.w >> 8], 1);
        } else {
            #pragma unroll
            for (int k = 0; k < 4; ++k) {
                if (j + k < cnt) {
                    ed[i*4+k] = dst[base + j + k];
                    es[i*4+k] = src[base + j + k];
                    atomicAdd(&h[ed[i*4+k] >> 8], 1);
                } else ed[i*4+k] = -1;
            }
        }
    }
    __syncthreads();
    int v = 0;
    if (t < MAXB) { v = (t < NB) ? h[t] : 0; tmp[t] = v; }
    __syncthreads();
    for (int off = 1; off < MAXB; off <<= 1) {
        int a = 0;
        if (t < MAXB && t >= off) a = tmp[t - off];
        __syncthreads();
        if (t < MAXB) tmp[t] += a;
        __syncthreads();
    }
    if (t < NB) {
        int excl = tmp[t] - v;
        lofs[t] = excl;
        cur[t] = excl;
        int g = v ? atomicAdd(&bcursor[t], v) : 0;   // reserve run in slack region
        delta[t] = g - excl;
    }
    __syncthreads();
    #pragma unroll
    for (int i = 0; i < 16; ++i) {
        int d = ed[i];
        if (d >= 0) {
            int b = d >> 8;
            int r = atomicAdd(&cur[b], 1);
            pk[r] = ((unsigned)(d & 255) << 24) | (unsigned)es[i];
        }
    }
    __syncthreads();
    int wid = t >> 6, lane = t & 63;
    for (int b = wid; b < NB; b += 16) {
        int s = lofs[b];
        int e2 = (b + 1 < NB) ? lofs[b + 1] : cnt;
        int dlt = delta[b];
        int lim = (b + 1) * CAPB;                    // overflow guard (never hit)
        for (int k = s + lane; k < e2; k += 64) {
            int gidx = dlt + k;
            if (gidx < lim) part[gidx] = pk[k];
        }
    }
}

// Phase B fused: 512-key counting sort (key = dstLocal*2 + (src>=HALF)) in LDS,
// sorted_src write-out, then LAYER-1 GATHER from the LDS-resident edge list and
// DENSE1 (+norm+relu) — agg1 never touches global. Emits deg/offs/nlo,
// sorted_src, hbuf (fp32) and hb (bf16 gather table for layer 2).
__global__ __launch_bounds__(1024) void partitionB_fused(
        const unsigned* __restrict__ part, const int* __restrict__ bcursor,
        const uint4* __restrict__ xb4, const float* __restrict__ x,
        const float* __restrict__ W1l, const float* __restrict__ b1,
        const float* __restrict__ W1r,
        int* __restrict__ deg, int* __restrict__ offs, int* __restrict__ nlo,
        int* __restrict__ sorted_src, float* __restrict__ hbuf,
        unsigned short* __restrict__ hb, int N, int HALF) {
    __shared__ int pk2[CAPB];                          // 72 KB staging
    __shared__ int hh[512], tmp[512], keyofs[512];
    __shared__ int lstart[256], ldeg[256];
    __shared__ float sagg[256 * 17];                   // agg1 sums, stride 17
    __shared__ float sx[256 * 14];                     // x rows
    __shared__ float swl[448], swr[448], sb1[32];
    int b = blockIdx.x;
    int t = threadIdx.x;
    int start = b * CAPB;
    int end = bcursor[b];
    if (end > start + CAPB) end = start + CAPB;
    int cnt = end - start;
    unsigned ce[18];
    if (t < 512) hh[t] = 0;
    if (t < 448) { swl[t] = W1l[t]; swr[t] = W1r[t]; }
    else if (t < 480) sb1[t - 448] = b1[t - 448];
    __syncthreads();
    #pragma unroll
    for (int i = 0; i < 18; ++i) {
        int idx = start + t + i * 1024;
        unsigned p = 0xFFFFFFFFu;
        if (idx < end) {
            p = part[idx];
            int key = (int)(p >> 24) * 2 + (((int)(p & 0xFFFFFFu) < HALF) ? 0 : 1);
            atomicAdd(&hh[key], 1);
        }
        ce[i] = p;
    }
    {   // stage x rows for this bucket (independent of histogram)
        int nnod = N - b * 256; if (nnod > 256) nnod = 256; if (nnod < 0) nnod = 0;
        const float* gx = x + (size_t)b * 256 * 14;
        for (int i = t; i < nnod * 14; i += 1024) sx[i] = gx[i];
    }
    __syncthreads();
    int v = (t < 512) ? hh[t] : 0;
    if (t < 512) tmp[t] = v;
    __syncthreads();
    for (int off = 1; off < 512; off <<= 1) {
        int a2 = (t < 512 && t >= off) ? tmp[t - off] : 0;
        __syncthreads();
        if (t < 512) tmp[t] += a2;
        __syncthreads();
    }
    if (t < 512) keyofs[t] = tmp[t] - v;               // exclusive per key
    __syncthreads();
    if (t < 256) {
        int lo = hh[2 * t];
        int d = lo + hh[2 * t + 1];
        int excl = keyofs[2 * t];
        lstart[t] = excl;
        ldeg[t] = d;
        int node = b * 256 + t;
        if (node < N) {
            deg[node] = d;
            offs[node] = start + excl;
            nlo[node] = lo;
        }
    }
    __syncthreads();
    #pragma unroll
    for (int i = 0; i < 18; ++i) {
        unsigned p = ce[i];
        if (p != 0xFFFFFFFFu) {
            int s = (int)(p & 0xFFFFFFu);
            int key = (int)(p >> 24) * 2 + ((s < HALF) ? 0 : 1);
            int r = atomicAdd(&keyofs[key], 1);
            pk2[r] = s;
        }
    }
    __syncthreads();
    for (int i = t; i < cnt; i += 1024)
        sorted_src[start + i] = pk2[i];

    // ---- fused layer-1 gather: 4 threads/node = 2 edge-streams x 2 row-halves
    int node = t >> 2, sub = t & 3, ep = sub >> 1, half = sub & 1;
    int js = lstart[node], d = ldeg[node];
    int je = js + d;
    float a[8] = {0,0,0,0,0,0,0,0};
    int j = js + ep;
    for (; j + 6 < je; j += 8) {
        int s0 = pk2[j], s1 = pk2[j+2], s2 = pk2[j+4], s3 = pk2[j+6];
        uint4 u0 = xb4[s0*2+half], u1 = xb4[s1*2+half], u2 = xb4[s2*2+half], u3 = xb4[s3*2+half];
        a[0] += BF_LO(u0.x)+BF_LO(u1.x)+BF_LO(u2.x)+BF_LO(u3.x);
        a[1] += BF_HI(u0.x)+BF_HI(u1.x)+BF_HI(u2.x)+BF_HI(u3.x);
        a[2] += BF_LO(u0.y)+BF_LO(u1.y)+BF_LO(u2.y)+BF_LO(u3.y);
        a[3] += BF_HI(u0.y)+BF_HI(u1.y)+BF_HI(u2.y)+BF_HI(u3.y);
        a[4] += BF_LO(u0.z)+BF_LO(u1.z)+BF_LO(u2.z)+BF_LO(u3.z);
        a[5] += BF_HI(u0.z)+BF_HI(u1.z)+BF_HI(u2.z)+BF_HI(u3.z);
        a[6] += BF_LO(u0.w)+BF_LO(u1.w)+BF_LO(u2.w)+BF_LO(u3.w);
        a[7] += BF_HI(u0.w)+BF_HI(u1.w)+BF_HI(u2.w)+BF_HI(u3.w);
    }
    for (; j < je; j += 2) {
        uint4 u0 = xb4[pk2[j]*2+half];
        a[0] += BF_LO(u0.x); a[1] += BF_HI(u0.x);
        a[2] += BF_LO(u0.y); a[3] += BF_HI(u0.y);
        a[4] += BF_LO(u0.z); a[5] += BF_HI(u0.z);
        a[6] += BF_LO(u0.w); a[7] += BF_HI(u0.w);
    }
    #pragma unroll
    for (int i = 0; i < 8; ++i) a[i] += __shfl_xor(a[i], 2);   // merge edge-streams
    if (ep == 0) {
        #pragma unroll
        for (int i = 0; i < 8; ++i) sagg[node * 17 + half * 8 + i] = a[i];
    }
    __syncthreads();

    // ---- fused dense1: thread (node, sub) computes 8 of 32 outputs
    float inv = 1.0f / ((d > 0) ? (float)d : 1.0f);
    float acc[8];
    #pragma unroll
    for (int i = 0; i < 8; ++i) acc[i] = sb1[sub * 8 + i];
    #pragma unroll
    for (int k = 0; k < 14; ++k) {
        float ag = sagg[node * 17 + k] * inv;
        float xv = sx[node * 14 + k];
        const float4* wl4 = (const float4*)&swl[k * 32 + sub * 8];
        const float4* wr4 = (const float4*)&swr[k * 32 + sub * 8];
        float4 wla = wl4[0], wlb = wl4[1], wra = wr4[0], wrb = wr4[1];
        acc[0] += ag * wla.x + xv * wra.x;
        acc[1] += ag * wla.y + xv * wra.y;
        acc[2] += ag * wla.z + xv * wra.z;
        acc[3] += ag * wla.w + xv * wra.w;
        acc[4] += ag * wlb.x + xv * wrb.x;
        acc[5] += ag * wlb.y + xv * wrb.y;
        acc[6] += ag * wlb.z + xv * wrb.z;
        acc[7] += ag * wlb.w + xv * wrb.w;
    }
    float ss = 0.f;
    #pragma unroll
    for (int i = 0; i < 8; ++i) ss += acc[i] * acc[i];
    ss += __shfl_xor(ss, 1); ss += __shfl_xor(ss, 2);
    float invn = 1.f / fmaxf(sqrtf(ss), 1e-12f);
    int gnode = b * 256 + node;
    if (gnode < N) {
        float hv[8];
        #pragma unroll
        for (int i = 0; i < 8; ++i) hv[i] = fmaxf(acc[i] * invn, 0.f);
        float4* ho = (float4*)(hbuf + (size_t)gnode * 32 + sub * 8);
        ho[0] = make_float4(hv[0], hv[1], hv[2], hv[3]);
        ho[1] = make_float4(hv[4], hv[5], hv[6], hv[7]);
        uint4 pb;
        pb.x = (unsigned)f2bf(hv[0]) | ((unsigned)f2bf(hv[1]) << 16);
        pb.y = (unsigned)f2bf(hv[2]) | ((unsigned)f2bf(hv[3]) << 16);
        pb.z = (unsigned)f2bf(hv[4]) | ((unsigned)f2bf(hv[5]) << 16);
        pb.w = (unsigned)f2bf(hv[6]) | ((unsigned)f2bf(hv[7]) << 16);
        *(uint4*)(hb + (size_t)gnode * 32 + sub * 8) = pb;
    }
}

// Layer-2 gather pass 0 (src < HALF; table half 3.2MB bf16, L2-resident).
// Writes raw sums to agg2.
__global__ void gather32_p0(const uint4* __restrict__ hb, const int* __restrict__ sorted_src,
                            const int* __restrict__ offs, const int* __restrict__ nlo,
                            float4* __restrict__ agg2, int N) {
    int idx = blockIdx.x * blockDim.x + threadIdx.x;
    int n = idx >> 2;
    if (n >= N) return;
    int q = idx & 3;
    int start = offs[n];
    int jend = nlo[n];
    float a0=0,a1=0,a2=0,a3=0,a4=0,a5=0,a6=0,a7=0;
    int j = 0;
    for (; j + 4 <= jend; j += 4) {
        int s0 = sorted_src[start + j + 0];
        int s1 = sorted_src[start + j + 1];
        int s2 = sorted_src[start + j + 2];
        int s3 = sorted_src[start + j + 3];
        uint4 u0 = hb[s0 * 4 + q];
        uint4 u1 = hb[s1 * 4 + q];
        uint4 u2 = hb[s2 * 4 + q];
        uint4 u3 = hb[s3 * 4 + q];
        a0 += BF_LO(u0.x) + BF_LO(u1.x) + BF_LO(u2.x) + BF_LO(u3.x);
        a1 += BF_HI(u0.x) + BF_HI(u1.x) + BF_HI(u2.x) + BF_HI(u3.x);
        a2 += BF_LO(u0.y) + BF_LO(u1.y) + BF_LO(u2.y) + BF_LO(u3.y);
        a3 += BF_HI(u0.y) + BF_HI(u1.y) + BF_HI(u2.y) + BF_HI(u3.y);
        a4 += BF_LO(u0.z) + BF_LO(u1.z) + BF_LO(u2.z) + BF_LO(u3.z);
        a5 += BF_HI(u0.z) + BF_HI(u1.z) + BF_HI(u2.z) + BF_HI(u3.z);
        a6 += BF_LO(u0.w) + BF_LO(u1.w) + BF_LO(u2.w) + BF_LO(u3.w);
        a7 += BF_HI(u0.w) + BF_HI(u1.w) + BF_HI(u2.w) + BF_HI(u3.w);
    }
    for (; j < jend; ++j) {
        uint4 u0 = hb[sorted_src[start + j] * 4 + q];
        a0 += BF_LO(u0.x); a1 += BF_HI(u0.x);
        a2 += BF_LO(u0.y); a3 += BF_HI(u0.y);
        a4 += BF_LO(u0.z); a5 += BF_HI(u0.z);
        a6 += BF_LO(u0.w); a7 += BF_HI(u0.w);
    }
    agg2[n * 8 + q * 2 + 0] = make_float4(a0, a1, a2, a3);
    agg2[n * 8 + q * 2 + 1] = make_float4(a4, a5, a6, a7);
}

// Layer-2 gather pass 1 (src >= HALF) + DENSE2 + final 32->2 linear fused.
// 4 lanes per node; register reduce-scatter via cndmask+shfl (no dynamic
// register indexing).
__global__ __launch_bounds__(256) void g32p1_dense2(
        const uint4* __restrict__ hb4, const int* __restrict__ sorted_src,
        const int* __restrict__ offs, const int* __restrict__ deg,
        const int* __restrict__ nlo, const float* __restrict__ agg2p,
        const float* __restrict__ hbuf,
        const float* __restrict__ W2l, const float* __restrict__ b2,
        const float* __restrict__ W2r, const float* __restrict__ Wlin,
        const float* __restrict__ blin, float* __restrict__ out, int N) {
    __shared__ float swl[1024], swr[1024], swo[64], sb2[32], sbo[2];
    int t = threadIdx.x;
    for (int i = t; i < 1024; i += 256) { swl[i] = W2l[i]; swr[i] = W2r[i]; }
    if (t < 64) swo[t] = Wlin[t];
    if (t < 32) sb2[t] = b2[t];
    if (t < 2) sbo[t] = blin[t];
    __syncthreads();
    int idx = blockIdx.x * 256 + t;
    int n = idx >> 2;
    if (n >= N) return;
    int q = idx & 3;
    int start = offs[n], d = deg[n], lo = nlo[n];
    float a[8] = {0,0,0,0,0,0,0,0};
    int j = lo;
    for (; j + 4 <= d; j += 4) {
        int s0 = sorted_src[start + j + 0];
        int s1 = sorted_src[start + j + 1];
        int s2 = sorted_src[start + j + 2];
        int s3 = sorted_src[start + j + 3];
        uint4 u0 = hb4[s0 * 4 + q];
        uint4 u1 = hb4[s1 * 4 + q];
        uint4 u2 = hb4[s2 * 4 + q];
        uint4 u3 = hb4[s3 * 4 + q];
        a[0] += BF_LO(u0.x)+BF_LO(u1.x)+BF_LO(u2.x)+BF_LO(u3.x);
        a[1] += BF_HI(u0.x)+BF_HI(u1.x)+BF_HI(u2.x)+BF_HI(u3.x);
        a[2] += BF_LO(u0.y)+BF_LO(u1.y)+BF_LO(u2.y)+BF_LO(u3.y);
        a[3] += BF_HI(u0.y)+BF_HI(u1.y)+BF_HI(u2.y)+BF_HI(u3.y);
        a[4] += BF_LO(u0.z)+BF_LO(u1.z)+BF_LO(u2.z)+BF_LO(u3.z);
        a[5] += BF_HI(u0.z)+BF_HI(u1.z)+BF_HI(u2.z)+BF_HI(u3.z);
        a[6] += BF_LO(u0.w)+BF_LO(u1.w)+BF_LO(u2.w)+BF_LO(u3.w);
        a[7] += BF_HI(u0.w)+BF_HI(u1.w)+BF_HI(u2.w)+BF_HI(u3.w);
    }
    for (; j < d; ++j) {
        uint4 u0 = hb4[sorted_src[start + j] * 4 + q];
        a[0] += BF_LO(u0.x); a[1] += BF_HI(u0.x);
        a[2] += BF_LO(u0.y); a[3] += BF_HI(u0.y);
        a[4] += BF_LO(u0.z); a[5] += BF_HI(u0.z);
        a[6] += BF_LO(u0.w); a[7] += BF_HI(u0.w);
    }
    float inv = 1.0f / ((d > 0) ? (float)d : 1.0f);
    const float4* gp = (const float4*)(agg2p + (size_t)n * 32 + q * 8);
    float4 p0 = gp[0], p1 = gp[1];
    float av[8];
    av[0] = (p0.x + a[0]) * inv; av[1] = (p0.y + a[1]) * inv;
    av[2] = (p0.z + a[2]) * inv; av[3] = (p0.w + a[3]) * inv;
    av[4] = (p1.x + a[4]) * inv; av[5] = (p1.y + a[5]) * inv;
    av[6] = (p1.z + a[6]) * inv; av[7] = (p1.w + a[7]) * inv;
    const float4* gh = (const float4*)(hbuf + (size_t)n * 32 + q * 8);
    float4 h0 = gh[0], h1 = gh[1];
    float hv8[8] = {h0.x, h0.y, h0.z, h0.w, h1.x, h1.y, h1.z, h1.w};
    float p[32];
    #pragma unroll
    for (int o = 0; o < 32; ++o) p[o] = 0.f;
    #pragma unroll
    for (int k = 0; k < 8; ++k) {
        int kk = q * 8 + k;
        const float4* wl4 = (const float4*)&swl[kk * 32];
        const float4* wr4 = (const float4*)&swr[kk * 32];
        #pragma unroll
        for (int o4 = 0; o4 < 8; ++o4) {
            float4 wl = wl4[o4], wr = wr4[o4];
            p[o4*4+0] += av[k] * wl.x + hv8[k] * wr.x;
            p[o4*4+1] += av[k] * wl.y + hv8[k] * wr.y;
            p[o4*4+2] += av[k] * wl.z + hv8[k] * wr.z;
            p[o4*4+3] += av[k] * wl.w + hv8[k] * wr.w;
        }
    }
    // reduce-scatter over the node quad: lane q ends with out[q*8 .. q*8+8)
    bool hi2 = (q & 2) != 0;
    float keep16[16];
    #pragma unroll
    for (int i = 0; i < 16; ++i) {
        float kv = hi2 ? p[i + 16] : p[i];
        float sv = hi2 ? p[i] : p[i + 16];
        keep16[i] = kv + __shfl_xor(sv, 2);
    }
    bool hi1 = (q & 1) != 0;
    float lin[8];
    #pragma unroll
    for (int i = 0; i < 8; ++i) {
        float kv = hi1 ? keep16[i + 8] : keep16[i];
        float sv = hi1 ? keep16[i] : keep16[i + 8];
        lin[i] = kv + __shfl_xor(sv, 1) + sb2[q * 8 + i];
    }
    float ss = 0.f;
    #pragma unroll
    for (int i = 0; i < 8; ++i) ss += lin[i] * lin[i];
    ss += __shfl_xor(ss, 1); ss += __shfl_xor(ss, 2);
    float invn = 1.f / fmaxf(sqrtf(ss), 1e-12f);
    float o0 = 0.f, o1 = 0.f;
    #pragma unroll
    for (int i = 0; i < 8; ++i) {
        float hv = fmaxf(lin[i] * invn, 0.f);
        int kk = q * 8 + i;
        o0 += hv * swo[kk * 2 + 0];
        o1 += hv * swo[kk * 2 + 1];
    }
    o0 += __shfl_xor(o0, 1); o0 += __shfl_xor(o0, 2);
    o1 += __shfl_xor(o1, 1); o1 += __shfl_xor(o1, 2);
    if (q == 0) {
        out[n * 2 + 0] = o0 + sbo[0];
        out[n * 2 + 1] = o1 + sbo[1];
    }
}

extern "C" void kernel_launch(void* const* d_in, const int* in_sizes, int n_in,
                              void* d_out, int out_size, void* d_ws, size_t ws_size,
                              hipStream_t stream) {
    const float* x    = (const float*)d_in[0];
    const int*   ei   = (const int*)d_in[1];
    const float* W1l  = (const float*)d_in[2];
    const float* b1   = (const float*)d_in[3];
    const float* W1r  = (const float*)d_in[4];
    const float* W2l  = (const float*)d_in[5];
    const float* b2   = (const float*)d_in[6];
    const float* W2r  = (const float*)d_in[7];
    const float* Wlin = (const float*)d_in[8];
    const float* blin = (const float*)d_in[9];
    float* out = (float*)d_out;

    const int N = in_sizes[0] / 14;
    const int E = in_sizes[1] / 2;
    const int* src = ei;
    const int* dst = ei + E;
    const int NB = (N + 255) / 256;   // 391 coarse buckets
    const int HALF = N / 2;

    char* ws = (char*)d_ws;
    size_t off = 0;
    auto alloc = [&](size_t bytes) -> void* {
        void* p = ws + off;
        off = (off + bytes + 255) & ~(size_t)255;
        return p;
    };
    int*            bcursor    = (int*)alloc((size_t)NB * 4);
    unsigned*       part       = (unsigned*)alloc((size_t)NB * CAPB * 4);  // slack; dead after partitionB_fused
    int*            sorted_src = (int*)alloc((size_t)NB * CAPB * 4);       // slack layout
    int*            deg        = (int*)alloc((size_t)N * 4);
    int*            offs       = (int*)alloc((size_t)N * 4);
    int*            nlo        = (int*)alloc((size_t)N * 4);
    unsigned short* xb         = (unsigned short*)alloc((size_t)N * 16 * 2);
    float*          hbuf       = (float*)alloc((size_t)N * 32 * 4);
    unsigned short* hb         = (unsigned short*)alloc((size_t)N * 32 * 2);
    float*          agg2       = (float*)part;                             // alias dead part buffer
    (void)ws_size; (void)n_in; (void)out_size;

    cvt_x_bf16<<<(N * 16 + 255) / 256, 256, 0, stream>>>(x, xb, bcursor, N, NB);
    partitionA<<<(E + CHA - 1) / CHA, 1024, 0, stream>>>(src, dst, bcursor, part, E, NB);
    partitionB_fused<<<NB, 1024, 0, stream>>>(
        part, bcursor, (const uint4*)xb, x, W1l, b1, W1r,
        deg, offs, nlo, sorted_src, hbuf, hb, N, HALF);
    gather32_p0<<<(N * 4 + 255) / 256, 256, 0, stream>>>(
        (const uint4*)hb, sorted_src, offs, nlo, (float4*)agg2, N);
    g32p1_dense2<<<(N * 4 + 255) / 256, 256, 0, stream>>>(
        (const uint4*)hb, sorted_src, offs, deg, nlo, agg2, hbuf,
        W2l, b2, W2r, Wlin, blin, out, N);
}

// Round 11
// 273.235 us; speedup vs baseline: 1.0927x; 1.0927x over previous
//
#include <hip/hip_runtime.h>
#include <hip/hip_bf16.h>

// GraphSAGE (2x SAGEConv mean + normalize + relu, final linear) on MI355X.
// R11: R10's dense2-into-gather fusion backfired (VGPR 116 -> occupancy 16%,
// 9.6M LDS bank conflicts from stride-256 weight reads) — the latency-bound
// gather needs occupancy more than fusion. Keep partitionB_fused (gather14 +
// dense1 inside the bucket sort — that half paid), revert the layer-2 tail to
// lean gather32_p1 + tiled dense2 (conflict-free padded strides).

#define CHA 16384   // edges per phase-A block
#define MAXB 512    // max coarse buckets (NB = ceil(N/256) = 391)
#define CAPB 18432  // slots per bucket region (mean fill ~16.4K, ~16 sigma margin)
#define NPB 128     // nodes per dense block

static __device__ __forceinline__ unsigned short f2bf(float f) {
    unsigned u = __float_as_uint(f);
    unsigned r = (u + 0x7FFFu + ((u >> 16) & 1u)) >> 16;   // RTN-even
    return (unsigned short)r;
}
#define BF_LO(u) __uint_as_float((u) << 16)
#define BF_HI(u) __uint_as_float((u) & 0xFFFF0000u)

// x [N x 14] fp32 -> xb [N x 16] bf16 (rows padded to 32B). Also inits bcursor.
__global__ void cvt_x_bf16(const float* __restrict__ x, unsigned short* __restrict__ xb,
                           int* __restrict__ bcursor, int N, int NB) {
    int idx = blockIdx.x * blockDim.x + threadIdx.x;
    if (idx < NB) bcursor[idx] = idx * CAPB;
    if (idx >= N * 16) return;
    int n = idx >> 4, f = idx & 15;
    float v = (f < 14) ? x[n * 14 + f] : 0.f;
    xb[idx] = f2bf(v);
}

// Phase A: per-block counting sort into LDS, coalesced per-run copy-out into
// the slack bucket regions. dst/src loaded ONCE as int4 into registers.
__global__ __launch_bounds__(1024) void partitionA(
        const int* __restrict__ src, const int* __restrict__ dst,
        int* __restrict__ bcursor, unsigned* __restrict__ part, int E, int NB) {
    __shared__ unsigned pk[CHA];                       // 64 KB staging
    __shared__ int h[MAXB], lofs[MAXB], cur[MAXB], delta[MAXB], tmp[MAXB];
    int t = threadIdx.x;
    int base = blockIdx.x * CHA;
    int end = base + CHA; if (end > E) end = E;
    int cnt = end - base;

    int ed[16], es[16];
    for (int i = t; i < NB; i += 1024) h[i] = 0;
    __syncthreads();
    #pragma unroll
    for (int i = 0; i < 4; ++i) {
        int j = i * 4096 + t * 4;
        if (j + 4 <= cnt) {
            int4 d4 = *(const int4*)(dst + base + j);
            int4 s4 = *(const int4*)(src + base + j);
            ed[i*4+0] = d4.x; ed[i*4+1] = d4.y; ed[i*4+2] = d4.z; ed[i*4+3] = d4.w;
            es[i*4+0] = s4.x; es[i*4+1] = s4.y; es[i*4+2] = s4.z; es[i*4+3] = s4.w;
            atomicAdd(&h[d4.x >> 8], 1);
            atomicAdd(&h[d4.y >> 8], 1);
            atomicAdd(&h[d4.z >> 8], 1);
            atomicAdd(&h[d4.w >> 8], 1);
        } else {
            #pragma unroll
            for (int k = 0; k < 4; ++k) {
                if (j + k < cnt) {
                    ed[i*4+k] = dst[base + j + k];
                    es[i*4+k] = src[base + j + k];
                    atomicAdd(&h[ed[i*4+k] >> 8], 1);
                } else ed[i*4+k] = -1;
            }
        }
    }
    __syncthreads();
    int v = 0;
    if (t < MAXB) { v = (t < NB) ? h[t] : 0; tmp[t] = v; }
    __syncthreads();
    for (int off = 1; off < MAXB; off <<= 1) {
        int a = 0;
        if (t < MAXB && t >= off) a = tmp[t - off];
        __syncthreads();
        if (t < MAXB) tmp[t] += a;
        __syncthreads();
    }
    if (t < NB) {
        int excl = tmp[t] - v;
        lofs[t] = excl;
        cur[t] = excl;
        int g = v ? atomicAdd(&bcursor[t], v) : 0;   // reserve run in slack region
        delta[t] = g - excl;
    }
    __syncthreads();
    #pragma unroll
    for (int i = 0; i < 16; ++i) {
        int d = ed[i];
        if (d >= 0) {
            int b = d >> 8;
            int r = atomicAdd(&cur[b], 1);
            pk[r] = ((unsigned)(d & 255) << 24) | (unsigned)es[i];
        }
    }
    __syncthreads();
    int wid = t >> 6, lane = t & 63;
    for (int b = wid; b < NB; b += 16) {
        int s = lofs[b];
        int e2 = (b + 1 < NB) ? lofs[b + 1] : cnt;
        int dlt = delta[b];
        int lim = (b + 1) * CAPB;                    // overflow guard (never hit)
        for (int k = s + lane; k < e2; k += 64) {
            int gidx = dlt + k;
            if (gidx < lim) part[gidx] = pk[k];
        }
    }
}

// Phase B fused: 512-key counting sort (key = dstLocal*2 + (src>=HALF)) in LDS,
// sorted_src write-out, then LAYER-1 GATHER from the LDS-resident edge list and
// DENSE1 (+norm+relu) — agg1 never touches global. Emits deg/offs/nlo,
// sorted_src, hbuf (fp32) and hb (bf16 gather table for layer 2).
__global__ __launch_bounds__(1024) void partitionB_fused(
        const unsigned* __restrict__ part, const int* __restrict__ bcursor,
        const uint4* __restrict__ xb4, const float* __restrict__ x,
        const float* __restrict__ W1l, const float* __restrict__ b1,
        const float* __restrict__ W1r,
        int* __restrict__ deg, int* __restrict__ offs, int* __restrict__ nlo,
        int* __restrict__ sorted_src, float* __restrict__ hbuf,
        unsigned short* __restrict__ hb, int N, int HALF) {
    __shared__ int pk2[CAPB];                          // 72 KB staging
    __shared__ int hh[512], tmp[512], keyofs[512];
    __shared__ int lstart[256], ldeg[256];
    __shared__ float sagg[256 * 17];                   // agg1 sums, stride 17
    __shared__ float sx[256 * 14];                     // x rows
    __shared__ float swl[448], swr[448], sb1[32];
    int b = blockIdx.x;
    int t = threadIdx.x;
    int start = b * CAPB;
    int end = bcursor[b];
    if (end > start + CAPB) end = start + CAPB;
    int cnt = end - start;
    unsigned ce[18];
    if (t < 512) hh[t] = 0;
    if (t < 448) { swl[t] = W1l[t]; swr[t] = W1r[t]; }
    else if (t < 480) sb1[t - 448] = b1[t - 448];
    __syncthreads();
    #pragma unroll
    for (int i = 0; i < 18; ++i) {
        int idx = start + t + i * 1024;
        unsigned p = 0xFFFFFFFFu;
        if (idx < end) {
            p = part[idx];
            int key = (int)(p >> 24) * 2 + (((int)(p & 0xFFFFFFu) < HALF) ? 0 : 1);
            atomicAdd(&hh[key], 1);
        }
        ce[i] = p;
    }
    {   // stage x rows for this bucket (independent of histogram)
        int nnod = N - b * 256; if (nnod > 256) nnod = 256; if (nnod < 0) nnod = 0;
        const float* gx = x + (size_t)b * 256 * 14;
        for (int i = t; i < nnod * 14; i += 1024) sx[i] = gx[i];
    }
    __syncthreads();
    int v = (t < 512) ? hh[t] : 0;
    if (t < 512) tmp[t] = v;
    __syncthreads();
    for (int off = 1; off < 512; off <<= 1) {
        int a2 = (t < 512 && t >= off) ? tmp[t - off] : 0;
        __syncthreads();
        if (t < 512) tmp[t] += a2;
        __syncthreads();
    }
    if (t < 512) keyofs[t] = tmp[t] - v;               // exclusive per key
    __syncthreads();
    if (t < 256) {
        int lo = hh[2 * t];
        int d = lo + hh[2 * t + 1];
        int excl = keyofs[2 * t];
        lstart[t] = excl;
        ldeg[t] = d;
        int node = b * 256 + t;
        if (node < N) {
            deg[node] = d;
            offs[node] = start + excl;
            nlo[node] = lo;
        }
    }
    __syncthreads();
    #pragma unroll
    for (int i = 0; i < 18; ++i) {
        unsigned p = ce[i];
        if (p != 0xFFFFFFFFu) {
            int s = (int)(p & 0xFFFFFFu);
            int key = (int)(p >> 24) * 2 + ((s < HALF) ? 0 : 1);
            int r = atomicAdd(&keyofs[key], 1);
            pk2[r] = s;
        }
    }
    __syncthreads();
    for (int i = t; i < cnt; i += 1024)
        sorted_src[start + i] = pk2[i];

    // ---- fused layer-1 gather: 4 threads/node = 2 edge-streams x 2 row-halves
    int node = t >> 2, sub = t & 3, ep = sub >> 1, half = sub & 1;
    int js = lstart[node], d = ldeg[node];
    int je = js + d;
    float a[8] = {0,0,0,0,0,0,0,0};
    int j = js + ep;
    for (; j + 6 < je; j += 8) {
        int s0 = pk2[j], s1 = pk2[j+2], s2 = pk2[j+4], s3 = pk2[j+6];
        uint4 u0 = xb4[s0*2+half], u1 = xb4[s1*2+half], u2 = xb4[s2*2+half], u3 = xb4[s3*2+half];
        a[0] += BF_LO(u0.x)+BF_LO(u1.x)+BF_LO(u2.x)+BF_LO(u3.x);
        a[1] += BF_HI(u0.x)+BF_HI(u1.x)+BF_HI(u2.x)+BF_HI(u3.x);
        a[2] += BF_LO(u0.y)+BF_LO(u1.y)+BF_LO(u2.y)+BF_LO(u3.y);
        a[3] += BF_HI(u0.y)+BF_HI(u1.y)+BF_HI(u2.y)+BF_HI(u3.y);
        a[4] += BF_LO(u0.z)+BF_LO(u1.z)+BF_LO(u2.z)+BF_LO(u3.z);
        a[5] += BF_HI(u0.z)+BF_HI(u1.z)+BF_HI(u2.z)+BF_HI(u3.z);
        a[6] += BF_LO(u0.w)+BF_LO(u1.w)+BF_LO(u2.w)+BF_LO(u3.w);
        a[7] += BF_HI(u0.w)+BF_HI(u1.w)+BF_HI(u2.w)+BF_HI(u3.w);
    }
    for (; j < je; j += 2) {
        uint4 u0 = xb4[pk2[j]*2+half];
        a[0] += BF_LO(u0.x); a[1] += BF_HI(u0.x);
        a[2] += BF_LO(u0.y); a[3] += BF_HI(u0.y);
        a[4] += BF_LO(u0.z); a[5] += BF_HI(u0.z);
        a[6] += BF_LO(u0.w); a[7] += BF_HI(u0.w);
    }
    #pragma unroll
    for (int i = 0; i < 8; ++i) a[i] += __shfl_xor(a[i], 2);   // merge edge-streams
    if (ep == 0) {
        #pragma unroll
        for (int i = 0; i < 8; ++i) sagg[node * 17 + half * 8 + i] = a[i];
    }
    __syncthreads();

    // ---- fused dense1: thread (node, sub) computes 8 of 32 outputs
    float inv = 1.0f / ((d > 0) ? (float)d : 1.0f);
    float acc[8];
    #pragma unroll
    for (int i = 0; i < 8; ++i) acc[i] = sb1[sub * 8 + i];
    #pragma unroll
    for (int k = 0; k < 14; ++k) {
        float ag = sagg[node * 17 + k] * inv;
        float xv = sx[node * 14 + k];
        const float4* wl4 = (const float4*)&swl[k * 32 + sub * 8];
        const float4* wr4 = (const float4*)&swr[k * 32 + sub * 8];
        float4 wla = wl4[0], wlb = wl4[1], wra = wr4[0], wrb = wr4[1];
        acc[0] += ag * wla.x + xv * wra.x;
        acc[1] += ag * wla.y + xv * wra.y;
        acc[2] += ag * wla.z + xv * wra.z;
        acc[3] += ag * wla.w + xv * wra.w;
        acc[4] += ag * wlb.x + xv * wrb.x;
        acc[5] += ag * wlb.y + xv * wrb.y;
        acc[6] += ag * wlb.z + xv * wrb.z;
        acc[7] += ag * wlb.w + xv * wrb.w;
    }
    float ss = 0.f;
    #pragma unroll
    for (int i = 0; i < 8; ++i) ss += acc[i] * acc[i];
    ss += __shfl_xor(ss, 1); ss += __shfl_xor(ss, 2);
    float invn = 1.f / fmaxf(sqrtf(ss), 1e-12f);
    int gnode = b * 256 + node;
    if (gnode < N) {
        float hv[8];
        #pragma unroll
        for (int i = 0; i < 8; ++i) hv[i] = fmaxf(acc[i] * invn, 0.f);
        float4* ho = (float4*)(hbuf + (size_t)gnode * 32 + sub * 8);
        ho[0] = make_float4(hv[0], hv[1], hv[2], hv[3]);
        ho[1] = make_float4(hv[4], hv[5], hv[6], hv[7]);
        uint4 pb;
        pb.x = (unsigned)f2bf(hv[0]) | ((unsigned)f2bf(hv[1]) << 16);
        pb.y = (unsigned)f2bf(hv[2]) | ((unsigned)f2bf(hv[3]) << 16);
        pb.z = (unsigned)f2bf(hv[4]) | ((unsigned)f2bf(hv[5]) << 16);
        pb.w = (unsigned)f2bf(hv[6]) | ((unsigned)f2bf(hv[7]) << 16);
        *(uint4*)(hb + (size_t)gnode * 32 + sub * 8) = pb;
    }
}

// Layer-2 gather pass 0 (src < HALF; table half 3.2MB bf16, L2-resident).
// Writes raw sums to agg2.
__global__ void gather32_p0(const uint4* __restrict__ hb, const int* __restrict__ sorted_src,
                            const int* __restrict__ offs, const int* __restrict__ nlo,
                            float4* __restrict__ agg2, int N) {
    int idx = blockIdx.x * blockDim.x + threadIdx.x;
    int n = idx >> 2;
    if (n >= N) return;
    int q = idx & 3;
    int start = offs[n];
    int jend = nlo[n];
    float a0=0,a1=0,a2=0,a3=0,a4=0,a5=0,a6=0,a7=0;
    int j = 0;
    for (; j + 4 <= jend; j += 4) {
        int s0 = sorted_src[start + j + 0];
        int s1 = sorted_src[start + j + 1];
        int s2 = sorted_src[start + j + 2];
        int s3 = sorted_src[start + j + 3];
        uint4 u0 = hb[s0 * 4 + q];
        uint4 u1 = hb[s1 * 4 + q];
        uint4 u2 = hb[s2 * 4 + q];
        uint4 u3 = hb[s3 * 4 + q];
        a0 += BF_LO(u0.x) + BF_LO(u1.x) + BF_LO(u2.x) + BF_LO(u3.x);
        a1 += BF_HI(u0.x) + BF_HI(u1.x) + BF_HI(u2.x) + BF_HI(u3.x);
        a2 += BF_LO(u0.y) + BF_LO(u1.y) + BF_LO(u2.y) + BF_LO(u3.y);
        a3 += BF_HI(u0.y) + BF_HI(u1.y) + BF_HI(u2.y) + BF_HI(u3.y);
        a4 += BF_LO(u0.z) + BF_LO(u1.z) + BF_LO(u2.z) + BF_LO(u3.z);
        a5 += BF_HI(u0.z) + BF_HI(u1.z) + BF_HI(u2.z) + BF_HI(u3.z);
        a6 += BF_LO(u0.w) + BF_LO(u1.w) + BF_LO(u2.w) + BF_LO(u3.w);
        a7 += BF_HI(u0.w) + BF_HI(u1.w) + BF_HI(u2.w) + BF_HI(u3.w);
    }
    for (; j < jend; ++j) {
        uint4 u0 = hb[sorted_src[start + j] * 4 + q];
        a0 += BF_LO(u0.x); a1 += BF_HI(u0.x);
        a2 += BF_LO(u0.y); a3 += BF_HI(u0.y);
        a4 += BF_LO(u0.z); a5 += BF_HI(u0.z);
        a6 += BF_LO(u0.w); a7 += BF_HI(u0.w);
    }
    agg2[n * 8 + q * 2 + 0] = make_float4(a0, a1, a2, a3);
    agg2[n * 8 + q * 2 + 1] = make_float4(a4, a5, a6, a7);
}

// Layer-2 gather pass 1 (src >= HALF): adds to pass-0 sums, applies 1/deg.
__global__ void gather32_p1(const uint4* __restrict__ hb, const int* __restrict__ sorted_src,
                            const int* __restrict__ offs, const int* __restrict__ deg,
                            const int* __restrict__ nlo, float4* __restrict__ agg2, int N) {
    int idx = blockIdx.x * blockDim.x + threadIdx.x;
    int n = idx >> 2;
    if (n >= N) return;
    int q = idx & 3;
    int start = offs[n];
    int d = deg[n];
    int j = nlo[n];
    float a0=0,a1=0,a2=0,a3=0,a4=0,a5=0,a6=0,a7=0;
    for (; j + 4 <= d; j += 4) {
        int s0 = sorted_src[start + j + 0];
        int s1 = sorted_src[start + j + 1];
        int s2 = sorted_src[start + j + 2];
        int s3 = sorted_src[start + j + 3];
        uint4 u0 = hb[s0 * 4 + q];
        uint4 u1 = hb[s1 * 4 + q];
        uint4 u2 = hb[s2 * 4 + q];
        uint4 u3 = hb[s3 * 4 + q];
        a0 += BF_LO(u0.x) + BF_LO(u1.x) + BF_LO(u2.x) + BF_LO(u3.x);
        a1 += BF_HI(u0.x) + BF_HI(u1.x) + BF_HI(u2.x) + BF_HI(u3.x);
        a2 += BF_LO(u0.y) + BF_LO(u1.y) + BF_LO(u2.y) + BF_LO(u3.y);
        a3 += BF_HI(u0.y) + BF_HI(u1.y) + BF_HI(u2.y) + BF_HI(u3.y);
        a4 += BF_LO(u0.z) + BF_LO(u1.z) + BF_LO(u2.z) + BF_LO(u3.z);
        a5 += BF_HI(u0.z) + BF_HI(u1.z) + BF_HI(u2.z) + BF_HI(u3.z);
        a6 += BF_LO(u0.w) + BF_LO(u1.w) + BF_LO(u2.w) + BF_LO(u3.w);
        a7 += BF_HI(u0.w) + BF_HI(u1.w) + BF_HI(u2.w) + BF_HI(u3.w);
    }
    for (; j < d; ++j) {
        uint4 u0 = hb[sorted_src[start + j] * 4 + q];
        a0 += BF_LO(u0.x); a1 += BF_HI(u0.x);
        a2 += BF_LO(u0.y); a3 += BF_HI(u0.y);
        a4 += BF_LO(u0.z); a5 += BF_HI(u0.z);
        a6 += BF_LO(u0.w); a7 += BF_HI(u0.w);
    }
    float inv = 1.0f / ((d > 0) ? (float)d : 1.0f);
    float4 p0 = agg2[n * 8 + q * 2 + 0];
    float4 p1 = agg2[n * 8 + q * 2 + 1];
    agg2[n * 8 + q * 2 + 0] = make_float4((p0.x + a0) * inv, (p0.y + a1) * inv,
                                          (p0.z + a2) * inv, (p0.w + a3) * inv);
    agg2[n * 8 + q * 2 + 1] = make_float4((p1.x + a4) * inv, (p1.y + a5) * inv,
                                          (p1.z + a6) * inv, (p1.w + a7) * inv);
}

// Layer 2 + final linear, tiled (conflict-free padded strides, VGPR ~36).
__global__ __launch_bounds__(256) void dense2(
        const float* __restrict__ h, const float* __restrict__ agg2,
        const float* __restrict__ W2l, const float* __restrict__ b2,
        const float* __restrict__ W2r, const float* __restrict__ Wlin,
        const float* __restrict__ blin, float* __restrict__ out, int N) {
    __shared__ float sa[NPB * 33];
    __shared__ float sh2[NPB * 33];
    __shared__ float swl[32 * 32], swr[32 * 32], swo[64], sb[32], sbo[2];
    int t = threadIdx.x;
    int nb = blockIdx.x * NPB;
    int nn = N - nb; if (nn > NPB) nn = NPB;
    const float4* ga = (const float4*)(agg2 + (size_t)nb * 32);
    const float4* gh = (const float4*)(h + (size_t)nb * 32);
    for (int i = t; i < nn * 8; i += 256) {
        float4 v = ga[i];
        float* d = &sa[(i >> 3) * 33 + (i & 7) * 4];
        d[0] = v.x; d[1] = v.y; d[2] = v.z; d[3] = v.w;
        float4 w = gh[i];
        float* e = &sh2[(i >> 3) * 33 + (i & 7) * 4];
        e[0] = w.x; e[1] = w.y; e[2] = w.z; e[3] = w.w;
    }
    for (int i = t; i < 1024; i += 256) { swl[i] = W2l[i]; swr[i] = W2r[i]; }
    if (t < 64) swo[t] = Wlin[t];
    if (t < 32) sb[t] = b2[t];
    if (t < 2) sbo[t] = blin[t];
    __syncthreads();
    int q2 = t & 3;
    int p = t >> 2;
    int l0 = p * 2, l1 = l0 + 1;
    float acc0[8], acc1[8];
    #pragma unroll
    for (int j = 0; j < 8; ++j) { acc0[j] = sb[q2 * 8 + j]; acc1[j] = acc0[j]; }
    for (int k = 0; k < 32; ++k) {
        float a0 = sa[l0 * 33 + k],  a1 = sa[l1 * 33 + k];
        float h0 = sh2[l0 * 33 + k], h1 = sh2[l1 * 33 + k];
        const float4* wl4 = (const float4*)&swl[k * 32 + q2 * 8];
        const float4* wr4 = (const float4*)&swr[k * 32 + q2 * 8];
        float4 wla = wl4[0], wlb = wl4[1], wra = wr4[0], wrb = wr4[1];
        acc0[0] += a0 * wla.x + h0 * wra.x;  acc1[0] += a1 * wla.x + h1 * wra.x;
        acc0[1] += a0 * wla.y + h0 * wra.y;  acc1[1] += a1 * wla.y + h1 * wra.y;
        acc0[2] += a0 * wla.z + h0 * wra.z;  acc1[2] += a1 * wla.z + h1 * wra.z;
        acc0[3] += a0 * wla.w + h0 * wra.w;  acc1[3] += a1 * wla.w + h1 * wra.w;
        acc0[4] += a0 * wlb.x + h0 * wrb.x;  acc1[4] += a1 * wlb.x + h1 * wrb.x;
        acc0[5] += a0 * wlb.y + h0 * wrb.y;  acc1[5] += a1 * wlb.y + h1 * wrb.y;
        acc0[6] += a0 * wlb.z + h0 * wrb.z;  acc1[6] += a1 * wlb.z + h1 * wrb.z;
        acc0[7] += a0 * wlb.w + h0 * wrb.w;  acc1[7] += a1 * wlb.w + h1 * wrb.w;
    }
    float ss0 = 0.f, ss1 = 0.f;
    #pragma unroll
    for (int j = 0; j < 8; ++j) { ss0 += acc0[j] * acc0[j]; ss1 += acc1[j] * acc1[j]; }
    ss0 += __shfl_xor(ss0, 1); ss0 += __shfl_xor(ss0, 2);
    ss1 += __shfl_xor(ss1, 1); ss1 += __shfl_xor(ss1, 2);
    float inv0 = 1.f / fmaxf(sqrtf(ss0), 1e-12f);
    float inv1 = 1.f / fmaxf(sqrtf(ss1), 1e-12f);
    float o00 = 0.f, o01 = 0.f, o10 = 0.f, o11 = 0.f;
    #pragma unroll
    for (int j = 0; j < 8; ++j) {
        float hv0 = fmaxf(acc0[j] * inv0, 0.f);
        float hv1 = fmaxf(acc1[j] * inv1, 0.f);
        int kk = q2 * 8 + j;
        o00 += hv0 * swo[kk * 2 + 0];
        o01 += hv0 * swo[kk * 2 + 1];
        o10 += hv1 * swo[kk * 2 + 0];
        o11 += hv1 * swo[kk * 2 + 1];
    }
    o00 += __shfl_xor(o00, 1); o00 += __shfl_xor(o00, 2);
    o01 += __shfl_xor(o01, 1); o01 += __shfl_xor(o01, 2);
    o10 += __shfl_xor(o10, 1); o10 += __shfl_xor(o10, 2);
    o11 += __shfl_xor(o11, 1); o11 += __shfl_xor(o11, 2);
    if (q2 == 0) {
        int n0 = nb + l0, n1 = nb + l1;
        if (n0 < N) { out[n0 * 2 + 0] = o00 + sbo[0]; out[n0 * 2 + 1] = o01 + sbo[1]; }
        if (n1 < N) { out[n1 * 2 + 0] = o10 + sbo[0]; out[n1 * 2 + 1] = o11 + sbo[1]; }
    }
}

extern "C" void kernel_launch(void* const* d_in, const int* in_sizes, int n_in,
                              void* d_out, int out_size, void* d_ws, size_t ws_size,
                              hipStream_t stream) {
    const float* x    = (const float*)d_in[0];
    const int*   ei   = (const int*)d_in[1];
    const float* W1l  = (const float*)d_in[2];
    const float* b1   = (const float*)d_in[3];
    const float* W1r  = (const float*)d_in[4];
    const float* W2l  = (const float*)d_in[5];
    const float* b2   = (const float*)d_in[6];
    const float* W2r  = (const float*)d_in[7];
    const float* Wlin = (const float*)d_in[8];
    const float* blin = (const float*)d_in[9];
    float* out = (float*)d_out;

    const int N = in_sizes[0] / 14;
    const int E = in_sizes[1] / 2;
    const int* src = ei;
    const int* dst = ei + E;
    const int NB = (N + 255) / 256;   // 391 coarse buckets
    const int HALF = N / 2;

    char* ws = (char*)d_ws;
    size_t off = 0;
    auto alloc = [&](size_t bytes) -> void* {
        void* p = ws + off;
        off = (off + bytes + 255) & ~(size_t)255;
        return p;
    };
    int*            bcursor    = (int*)alloc((size_t)NB * 4);
    unsigned*       part       = (unsigned*)alloc((size_t)NB * CAPB * 4);  // slack; dead after partitionB_fused
    int*            sorted_src = (int*)alloc((size_t)NB * CAPB * 4);       // slack layout
    int*            deg        = (int*)alloc((size_t)N * 4);
    int*            offs       = (int*)alloc((size_t)N * 4);
    int*            nlo        = (int*)alloc((size_t)N * 4);
    unsigned short* xb         = (unsigned short*)alloc((size_t)N * 16 * 2);
    float*          hbuf       = (float*)alloc((size_t)N * 32 * 4);
    unsigned short* hb         = (unsigned short*)alloc((size_t)N * 32 * 2);
    float*          agg2       = (float*)part;                             // alias dead part buffer
    (void)ws_size; (void)n_in; (void)out_size;

    cvt_x_bf16<<<(N * 16 + 255) / 256, 256, 0, stream>>>(x, xb, bcursor, N, NB);
    partitionA<<<(E + CHA - 1) / CHA, 1024, 0, stream>>>(src, dst, bcursor, part, E, NB);
    partitionB_fused<<<NB, 1024, 0, stream>>>(
        part, bcursor, (const uint4*)xb, x, W1l, b1, W1r,
        deg, offs, nlo, sorted_src, hbuf, hb, N, HALF);
    gather32_p0<<<(N * 4 + 255) / 256, 256, 0, stream>>>(
        (const uint4*)hb, sorted_src, offs, nlo, (float4*)agg2, N);
    gather32_p1<<<(N * 4 + 255) / 256, 256, 0, stream>>>(
        (const uint4*)hb, sorted_src, offs, deg, nlo, (float4*)agg2, N);
    dense2<<<(N + NPB - 1) / NPB, 256, 0, stream>>>(
        hbuf, agg2, W2l, b2, W2r, Wlin, blin, out, N);
}